// Round 5
// baseline (965.294 us; speedup 1.0000x reference)
//
#include <hip/hip_runtime.h>
#include <hip/hip_bf16.h>
#include <stdint.h>
#include <math.h>

#define NB 16384      // batch
#define NSEQ 32       // sequence length
#define NV 1001       // vocab (V+1)
#define NROWS 32768   // 2 * NB flattened rows

typedef __attribute__((ext_vector_type(8))) short bf16x8;
typedef __attribute__((ext_vector_type(4))) float f32x4;

// ---------------- threefry2x32 (JAX-exact) ----------------
__device__ __forceinline__ void tf2x32(uint32_t k0, uint32_t k1,
                                       uint32_t x0, uint32_t x1,
                                       uint32_t& o0, uint32_t& o1) {
  const uint32_t ks0 = k0, ks1 = k1, ks2 = k0 ^ k1 ^ 0x1BD11BDAu;
  x0 += ks0; x1 += ks1;
  const int rA[4] = {13, 15, 26, 6};
  const int rB[4] = {17, 29, 16, 24};
#pragma unroll
  for (int i = 0; i < 4; ++i) { x0 += x1; x1 = (x1 << rA[i]) | (x1 >> (32 - rA[i])); x1 ^= x0; }
  x0 += ks1; x1 += ks2 + 1u;
#pragma unroll
  for (int i = 0; i < 4; ++i) { x0 += x1; x1 = (x1 << rB[i]) | (x1 >> (32 - rB[i])); x1 ^= x0; }
  x0 += ks2; x1 += ks0 + 2u;
#pragma unroll
  for (int i = 0; i < 4; ++i) { x0 += x1; x1 = (x1 << rA[i]) | (x1 >> (32 - rA[i])); x1 ^= x0; }
  x0 += ks0; x1 += ks1 + 3u;
#pragma unroll
  for (int i = 0; i < 4; ++i) { x0 += x1; x1 = (x1 << rB[i]) | (x1 >> (32 - rB[i])); x1 ^= x0; }
  x0 += ks1; x1 += ks2 + 4u;
#pragma unroll
  for (int i = 0; i < 4; ++i) { x0 += x1; x1 = (x1 << rA[i]) | (x1 >> (32 - rA[i])); x1 ^= x0; }
  o0 = x0 + ks2; o1 = x1 + ks0 + 5u;
}

__device__ __forceinline__ float gumbel_from_bits(uint32_t bits) {
  uint32_t fb = (bits >> 9) | 0x3f800000u;
  float u = __uint_as_float(fb) - 1.0f;
  u = fmaxf(u, 1.17549435e-38f);
  return -logf(-logf(u));
}

__device__ __forceinline__ float sigm(float x) { return 1.0f / (1.0f + __expf(-x)); }
__device__ __forceinline__ float tanh_(float x) {
  float e = __expf(2.0f * x);
  return 1.0f - 2.0f / (e + 1.0f);
}

__device__ __forceinline__ float dot64(const float* __restrict__ w, const float* h) {
  float a = 0.f;
#pragma unroll
  for (int k = 0; k < 64; ++k) a = fmaf(w[k], h[k], a);
  return a;
}

// round-to-bf16 (RNE): returns bits, outputs rounded-back float
__device__ __forceinline__ unsigned short bfbits(float x, float& xf) {
  __hip_bfloat16 hb = __float2bfloat16(x);
  xf = __bfloat162float(hb);
  unsigned short u;
  __builtin_memcpy(&u, &hb, 2);
  return u;
}

// LSTM cell epilogue — float expressions identical to r3 (bit-exact path)
__device__ __forceinline__ float lcell(const f32x4 A, const float4 es, float& c) {
  const float gi = A.x + es.x;
  const float gf = A.y + es.y;
  const float gg = A.z + es.z;
  const float go = A.w + es.w;
  const float ci = sigm(gf) * c + sigm(gi) * tanh_(gg);
  c = ci;
  return sigm(go) * tanh_(ci);
}

// Team-of-4 categorical sample + logprob (bit-exact since r3 — do not touch)
template <int N>
__device__ __forceinline__ void samp_team(const float* lg, int g, int C,
                                          uint32_t k0, uint32_t k1, int b,
                                          int& sOut, float& lpOut) {
  float m = -__builtin_inff();
#pragma unroll
  for (int i = 0; i < N; ++i) m = fmaxf(m, lg[i]);
  m = fmaxf(m, __shfl_xor(m, 1));
  m = fmaxf(m, __shfl_xor(m, 2));
  float se = 0.f;
#pragma unroll
  for (int i = 0; i < N; ++i) se += expf(lg[i] - m);
  se += __shfl_xor(se, 1);
  se += __shfl_xor(se, 2);
  const float lse = logf(se);
  float bz = -__builtin_inff(), bl = 0.f;
  int bi = 0x7fffffff;
#pragma unroll
  for (int i = 0; i < N; ++i) {
    const int c = g + 4 * i;
    uint32_t o0, o1; tf2x32(k0, k1, 0u, (uint32_t)(b * C + c), o0, o1);
    const float z = lg[i] + gumbel_from_bits(o0 ^ o1);
    if (z > bz || (z == bz && c < bi)) { bz = z; bi = c; bl = lg[i]; }
  }
#pragma unroll
  for (int d = 1; d <= 2; d <<= 1) {
    const float z2 = __shfl_xor(bz, d);
    const int i2 = __shfl_xor(bi, d);
    const float l2 = __shfl_xor(bl, d);
    if (z2 > bz || (z2 == bz && i2 < bi)) { bz = z2; bi = i2; bl = l2; }
  }
  sOut = bi;
  lpOut = (bl - m) - lse;
}

// ---------------- kernel A: packed precompute (identical to r9) ------------
// Gate-interleaved j' = unit*4 + gate (gate order i,f,g,o; torch j = gate*64+unit)
// embedWi[v][j'] = b_ih[j] + b_hh[j] + sum_k embed[v][k]*W_ih[j][k]   (fp32)
// Wsp[(s*256 + j')*64 + m]: m = kc*32 + q*8 + p holds split_s(W[j][k]) with
//   k = kc*32 + q*8 + cmap(p), cmap(p) = (p>>1) + ((p&1)<<2).
__global__ __launch_bounds__(256) void k_prep(
    const float* __restrict__ embed, const float* __restrict__ W_ih,
    const float* __restrict__ W_hh, const float* __restrict__ b_ih,
    const float* __restrict__ b_hh, float* __restrict__ embedWi,
    unsigned short* __restrict__ Wsp) {
  if (blockIdx.x >= NV) {
    int idx = (blockIdx.x - NV) * 256 + threadIdx.x;  // 0..49151
    int s = idx >> 14;
    int rem = idx & 16383;
    int jp = rem >> 6, m = rem & 63;
    int kc = m >> 5, q = (m >> 3) & 3, p = m & 7;
    int k = kc * 32 + q * 8 + ((p >> 1) + ((p & 1) << 2));
    int j = (jp & 3) * 64 + (jp >> 2);
    float w = W_hh[j * 64 + k];
    float f1, f2, f3;
    unsigned short b1 = bfbits(w, f1);
    unsigned short b2 = bfbits(w - f1, f2);
    unsigned short b3 = bfbits(w - f1 - f2, f3);
    Wsp[idx] = (s == 0) ? b1 : (s == 1) ? b2 : b3;
    return;
  }
  __shared__ float er[64];
  int v = blockIdx.x;
  if (threadIdx.x < 64) er[threadIdx.x] = embed[v * 64 + threadIdx.x];
  __syncthreads();
  int jp = threadIdx.x;
  int j = (jp & 3) * 64 + (jp >> 2);
  float a = b_ih[j] + b_hh[j];
#pragma unroll
  for (int k = 0; k < 64; ++k) a = fmaf(W_ih[j * 64 + k], er[k], a);
  embedWi[v * 256 + jp] = a;
}

// ---------------- kernel B: LSTM, single-wave recurrence, ZERO barriers ----
// r14: three scheduling nulls (r2 reorder, r3 pipeline, r4 SGB) prove the
// WG-barrier-per-timestep structure is the ceiling (8 waves phase-locked;
// Mfma 31 + VALU 72 = sum-not-max). r14 removes the barrier entirely: each
// wave owns 16 batch rows' FULL recurrence. Per timestep: 16 j'-tiles x 12
// MFMA (16x16x32); C/D layout gives each lane all 4 gates of unit 4jt+q at
// col n15 -> lane-local epilogue; h hand-off to the next B operand is a 4x4
// quad transpose (cmap pairs k,k+4 -> each B word = one source quad's pack)
// done with 48 shfl_xor + selects. No LDS, no syncthreads; A-frags (96KB
// Wsp) + es stream from L2 under the MFMA chains. 2048 waves = 2/SIMD,
// free-running. Operand bytes, MFMA product order (6 products: drop w2h3,
// w3h2, w3h3 — <= 2^-24 rel), and epilogue floats identical to r3 ->
// bit-exact. __launch_bounds__(64,2): VGPR cap 256 either-semantics.
#define MFMA16(A_, B_, C_) __builtin_amdgcn_mfma_f32_16x16x32_bf16(A_, B_, C_, 0, 0, 0)
__global__ __launch_bounds__(64, 2) void k_lstm(
    const int* __restrict__ inst0, const int* __restrict__ inst1,
    const float* __restrict__ embedWi, const unsigned short* __restrict__ Wsp,
    float* __restrict__ hT) {
  const int lane = threadIdx.x & 63;
  const int q = lane >> 4;        // quad 0..3
  const int n = lane & 15;        // batch-row within wave
  const int grow = blockIdx.x * 16 + n;            // flat row 0..32767
  const int* __restrict__ inst = (blockIdx.x < 1024) ? inst0 : inst1;
  const int rb_row = grow & (NB - 1);

  float cst[16];                  // cell state, unit 4jt+q per jt
#pragma unroll
  for (int i = 0; i < 16; ++i) cst[i] = 0.f;

  // B words [kc][s][w]: word w = pack(h_s[32kc+8q+w], h_s[32kc+8q+w+4])
  uint32_t bw[2][3][4];
#pragma unroll
  for (int kc = 0; kc < 2; ++kc)
#pragma unroll
    for (int s = 0; s < 3; ++s)
#pragma unroll
      for (int w = 0; w < 4; ++w) bw[kc][s][w] = 0u;   // h(0) = 0

  int vcur = inst[rb_row * NSEQ];

#pragma unroll 1
  for (int t = 0; t < NSEQ; ++t) {
    const bool last = (t == NSEQ - 1);
    const int vnxt = inst[rb_row * NSEQ + ((t + 1) & 31)];

    // assemble B operands (register moves only)
    bf16x8 B[2][3];
#pragma unroll
    for (int kc = 0; kc < 2; ++kc)
#pragma unroll
      for (int s = 0; s < 3; ++s) {
        union { uint32_t u[4]; bf16x8 v; } tmp;
#pragma unroll
        for (int w = 0; w < 4; ++w) tmp.u[w] = bw[kc][s][w];
        B[kc][s] = tmp.v;
      }

    // own h-split words destined for each quad: Wown[kc][qd][s]
    uint32_t Wown[2][4][3];
    unsigned short pb1 = 0, pb2 = 0, pb3 = 0;

#pragma unroll
    for (int jt = 0; jt < 16; ++jt) {
      // A-frags for this j'-tile: s in {0,1,2} x kc in {0,1}; L2-hot stream
      const unsigned short* wp = Wsp + (jt * 16 + n) * 64 + q * 8;
      const bf16x8 A00 = *(const bf16x8*)(wp);
      const bf16x8 A01 = *(const bf16x8*)(wp + 32);
      const bf16x8 A10 = *(const bf16x8*)(wp + 16384);
      const bf16x8 A11 = *(const bf16x8*)(wp + 16384 + 32);
      const bf16x8 A20 = *(const bf16x8*)(wp + 32768);
      const bf16x8 A21 = *(const bf16x8*)(wp + 32768 + 32);
      const float4 es = *(const float4*)(embedWi + vcur * 256 + jt * 16 + q * 4);

      f32x4 acc = (f32x4){0.f, 0.f, 0.f, 0.f};
      // kc=0 then kc=1; product order identical to r3: s0b2,s2b0,s1b1,s0b1,s1b0,s0b0
      acc = MFMA16(A00, B[0][2], acc);
      acc = MFMA16(A20, B[0][0], acc);
      acc = MFMA16(A10, B[0][1], acc);
      acc = MFMA16(A00, B[0][1], acc);
      acc = MFMA16(A10, B[0][0], acc);
      acc = MFMA16(A00, B[0][0], acc);
      acc = MFMA16(A01, B[1][2], acc);
      acc = MFMA16(A21, B[1][0], acc);
      acc = MFMA16(A11, B[1][1], acc);
      acc = MFMA16(A01, B[1][1], acc);
      acc = MFMA16(A11, B[1][0], acc);
      acc = MFMA16(A01, B[1][0], acc);

      const float hv = lcell(acc, es, cst[jt]);

      if (last) {
        hT[(4 * jt + q) * NROWS + grow] = hv;
      } else {
        float f1, f2, f3x;
        const unsigned short b1 = bfbits(hv, f1);
        const unsigned short b2 = bfbits(hv - f1, f2);
        const unsigned short b3 = bfbits(hv - f1 - f2, f3x);
        if (jt & 1) {
          // pair p = jt>>1: units (8p+q, 8p+4+q) -> kc = p>>2, qd = p&3
          constexpr int dummy = 0; (void)dummy;
          const int p_ = jt >> 1;
          const int kc_ = p_ >> 2, qd_ = p_ & 3;
          Wown[kc_][qd_][0] = (uint32_t)pb1 | ((uint32_t)b1 << 16);
          Wown[kc_][qd_][1] = (uint32_t)pb2 | ((uint32_t)b2 << 16);
          Wown[kc_][qd_][2] = (uint32_t)pb3 | ((uint32_t)b3 << 16);
        } else {
          pb1 = b1; pb2 = b2; pb3 = b3;
        }
      }
    }
    vcur = vnxt;

    if (!last) {
      // distributed 4x4 quad transpose: bw[kc][s][w] <- lane(w*16+n).Wown[kc][q][s]
#pragma unroll
      for (int kc = 0; kc < 2; ++kc)
#pragma unroll
        for (int s = 0; s < 3; ++s) {
          const uint32_t a0 = Wown[kc][0][s], a1 = Wown[kc][1][s];
          const uint32_t a2 = Wown[kc][2][s], a3 = Wown[kc][3][s];
          // stage 1: bit1 of quad (lane ^ 32)
          const uint32_t t0 = (uint32_t)__shfl_xor((int)a2, 32);
          const uint32_t t1 = (uint32_t)__shfl_xor((int)a3, 32);
          const uint32_t t2 = (uint32_t)__shfl_xor((int)a0, 32);
          const uint32_t t3 = (uint32_t)__shfl_xor((int)a1, 32);
          const bool hiq = (q & 2) != 0;
          const uint32_t c0 = hiq ? t0 : a0;
          const uint32_t c1 = hiq ? t1 : a1;
          const uint32_t c2 = hiq ? a2 : t2;
          const uint32_t c3 = hiq ? a3 : t3;
          // stage 2: bit0 of quad (lane ^ 16)
          const uint32_t u0 = (uint32_t)__shfl_xor((int)c1, 16);
          const uint32_t u1 = (uint32_t)__shfl_xor((int)c0, 16);
          const uint32_t u2 = (uint32_t)__shfl_xor((int)c3, 16);
          const uint32_t u3 = (uint32_t)__shfl_xor((int)c2, 16);
          const bool oq = (q & 1) != 0;
          bw[kc][s][0] = oq ? u0 : c0;
          bw[kc][s][1] = oq ? c1 : u1;
          bw[kc][s][2] = oq ? u2 : c2;
          bw[kc][s][3] = oq ? c3 : u3;
        }
    }
  }
}

// ---------------- kernel C: heads, 4-lane team per row (bit-exact r3+) -----
__global__ __launch_bounds__(256) void k_heads(
    const int* __restrict__ canvas0, const int* __restrict__ canvas1,
    const int* __restrict__ ref,
    const float* __restrict__ Wc, const float* __restrict__ bc,
    const float* __restrict__ Ws, const float* __restrict__ bs,
    const float* __restrict__ Wl, const float* __restrict__ bl,
    const float* __restrict__ Wr1, const float* __restrict__ br1,
    const float* __restrict__ Wr2, const float* __restrict__ br2,
    const float* __restrict__ Wp, const float* __restrict__ bp,
    const float* __restrict__ hT, float* __restrict__ out) {
  const int tid = threadIdx.x;
  const int g = tid & 3;
  const int s = blockIdx.x & 1;
  const int b = (blockIdx.x >> 1) * 64 + (tid >> 2);
  const float NEG = -__builtin_inff();

  uint32_t kk0[7], kk1[7];
#pragma unroll
  for (int i = 0; i < 7; ++i) {
    uint32_t o0, o1; tf2x32(0u, 42u, 0u, (uint32_t)i, o0, o1);
    kk0[i] = o0; kk1[i] = o1;
  }

  float h[64];
#pragma unroll
  for (int u = 0; u < 64; ++u) h[u] = hT[u * NROWS + s * NB + b];

  float lgc[1], lgs[1];
  lgc[0] = (g < 3) ? (bc[g] + dot64(Wc + g * 64, h)) : NEG;
  lgs[0] = (g < 3) ? (bs[g] + dot64(Ws + g * 64, h)) : NEG;

  if (s == 0) {
    int cs0, ss0, loc0; float clp0, slp0, llp0;
    samp_team<1>(lgc, g, 3, kk0[0], kk1[0], b, cs0, clp0);
    samp_team<1>(lgs, g, 3, kk0[1], kk1[1], b, ss0, slp0);
    float lgl[7];
#pragma unroll
    for (int i = 0; i < 7; ++i) {
      const int cc = g + 4 * i;
      lgl[i] = (cc < 25) ? (bl[cc] + dot64(Wl + cc * 64, h)) : NEG;
    }
    samp_team<7>(lgl, g, 25, kk0[2], kk1[2], b, loc0, llp0);

    if (g == 0) {
      const int p0 = min(max(loc0, 0), 24);
      const int4 pt = ((const int4*)(canvas1 + b * 100))[p0];
      const bool ok0 = (loc0 >= 0) && (loc0 < 25) && (pt.x + pt.y + pt.z + pt.w >= 0);
      const float loc_r0 = ok0 ? 1.f : -1.f;
      const float col_r0 = ok0 ? ((cs0 == pt.x) ? 1.f : -1.f) : 0.f;
      out[0 * NB + b] = clp0;
      out[1 * NB + b] = slp0;
      out[2 * NB + b] = llp0;
      out[7 * NB + b] = loc_r0;
      out[8 * NB + b] = col_r0;
      out[9 * NB + b] = loc_r0;
    }
  } else {
    int cs1, ss1, ls1; float clp1, slp1, llp1;
    samp_team<1>(lgc, g, 3, kk0[3], kk1[3], b, cs1, clp1);
    samp_team<1>(lgs, g, 3, kk0[4], kk1[4], b, ss1, slp1);
    float lgp[2];
#pragma unroll
    for (int i = 0; i < 2; ++i) {
      const int cc = g + 4 * i;
      lgp[i] = bp[cc] + dot64(Wp + cc * 64, h);
    }
    samp_team<2>(lgp, g, 8, kk0[5], kk1[5], b, ls1, llp1);

    float uv8[8], w64[8], w65[8], w66[8], w67[8], wr2[8];
#pragma unroll
    for (int i = 0; i < 8; ++i) {
      const int j = g + 4 * i;
      uv8[i] = br1[j] + dot64(Wr1 + j * 68, h);
      const float* wr = Wr1 + j * 68 + 64;
      w64[i] = wr[0]; w65[i] = wr[1]; w66[i] = wr[2]; w67[i] = wr[3];
      wr2[i] = Wr2[j];
    }
    float lgA[7];
#pragma unroll
    for (int i = 0; i < 7; ++i) lgA[i] = NEG;
    const float b2 = br2[0];
#pragma unroll
    for (int p = 0; p < 25; ++p) {
      const int4 c4 = ((const int4*)(canvas0 + b * 100))[p];
      const float f0 = (float)c4.x, f1 = (float)c4.y;
      const float f2 = (float)c4.z, f3 = (float)c4.w;
      float part = 0.f;
#pragma unroll
      for (int i = 0; i < 8; ++i) {
        float hj = uv8[i];
        hj = fmaf(w64[i], f0, hj);
        hj = fmaf(w65[i], f1, hj);
        hj = fmaf(w66[i], f2, hj);
        hj = fmaf(w67[i], f3, hj);
        part = fmaf(wr2[i], fmaxf(hj, 0.f), part);
      }
      part += __shfl_xor(part, 1);
      part += __shfl_xor(part, 2);
      const float ap = b2 + part;
      if ((p & 3) == g) lgA[p >> 2] = ap;
    }
    int att_s; float alp1;
    samp_team<7>(lgA, g, 25, kk0[6], kk1[6], b, att_s, alp1);

    if (g == 0) {
      const int4 r4 = ((const int4*)(canvas0 + b * 100))[att_s];
      const int4 rr = *(const int4*)(ref + b * 4);
      const bool match = (r4.x == rr.x) && (r4.y == rr.y) &&
                         (r4.z == rr.z) && (r4.w == rr.w);
      const float att_reward = match ? 1.f : -1.f;
      const int ox = (int)((0x22001120u >> (ls1 * 4)) & 0xFu) - 1;
      const int oy = (int)((0x20200211u >> (ls1 * 4)) & 0xFu) - 1;
      const int loc1 = (r4.z + ox) * 5 + (r4.w + oy);
      const int p1 = min(max(loc1, 0), 24);
      const int4 q4 = ((const int4*)(canvas1 + b * 100))[p1];
      const bool ok1 = (loc1 >= 0) && (loc1 < 25) && (q4.x + q4.y + q4.z + q4.w >= 0);
      const float loc_r1 = ok1 ? 1.f : -1.f;
      const float col_r1 = ok1 ? ((cs1 == q4.x) ? 1.f : -1.f) : 0.f;
      out[3 * NB + b]  = clp1;
      out[4 * NB + b]  = slp1;
      out[5 * NB + b]  = llp1;
      out[6 * NB + b]  = alp1;
      out[10 * NB + b] = loc_r1;
      out[11 * NB + b] = col_r1;
      out[12 * NB + b] = loc_r1;
      out[13 * NB + b] = att_reward;
    }
  }
}

extern "C" void kernel_launch(void* const* d_in, const int* in_sizes, int n_in,
                              void* d_out, int out_size, void* d_ws, size_t ws_size,
                              hipStream_t stream) {
  const int* inst0 = (const int*)d_in[0];
  const int* inst1 = (const int*)d_in[1];
  const int* canvas0 = (const int*)d_in[2];
  const int* canvas1 = (const int*)d_in[3];
  const int* ref = (const int*)d_in[4];
  const float* embed = (const float*)d_in[5];
  const float* W_ih = (const float*)d_in[6];
  const float* W_hh = (const float*)d_in[7];
  const float* b_ih = (const float*)d_in[8];
  const float* b_hh = (const float*)d_in[9];
  const float* Wc = (const float*)d_in[10];
  const float* bc = (const float*)d_in[11];
  const float* Ws = (const float*)d_in[12];
  const float* bs = (const float*)d_in[13];
  const float* Wl = (const float*)d_in[14];
  const float* bl = (const float*)d_in[15];
  const float* Wr1 = (const float*)d_in[16];
  const float* br1 = (const float*)d_in[17];
  const float* Wr2 = (const float*)d_in[18];
  const float* br2 = (const float*)d_in[19];
  const float* Wp = (const float*)d_in[20];
  const float* bp = (const float*)d_in[21];

  float* ws = (float*)d_ws;
  float* embedWi = ws;                               // 1001*256 fp32
  unsigned short* Wsp = (unsigned short*)(ws + NV * 256);  // 3*256*64 bf16
  float* hT = ws + NV * 256 + 24576;                 // 64*32768 fp32
  float* out = (float*)d_out;

  k_prep<<<NV + 192, 256, 0, stream>>>(embed, W_ih, W_hh, b_ih, b_hh, embedWi, Wsp);
  k_lstm<<<2048, 64, 0, stream>>>(inst0, inst1, embedWi, Wsp, hT);
  k_heads<<<512, 256, 0, stream>>>(canvas0, canvas1, ref, Wc, bc, Ws, bs,
                                   Wl, bl, Wr1, br1, Wr2, br2, Wp, bp, hT, out);
}

// Round 6
// 489.885 us; speedup vs baseline: 1.9705x; 1.9705x over previous
//
#include <hip/hip_runtime.h>
#include <hip/hip_bf16.h>
#include <stdint.h>
#include <math.h>

#define NB 16384      // batch
#define NSEQ 32       // sequence length
#define NV 1001       // vocab (V+1)
#define NROWS 32768   // 2 * NB flattened rows

// LDS h-buffer geometry (bytes), R=32 rows per WG
#define CHK 272           // chunk stride (16 rows x 16B + 16B pad)
#define RTG (8 * CHK)     // 2176: row-tile-group stride (8 k-chunks)
#define SPL (2 * RTG)     // 4352: split stride (2 row-tile-groups)
#define HBUF (3 * SPL)    // 13056: one h buffer (3 splits)
#define IDSOFF (2 * HBUF)         // idst: 32x32 ints (4KB)
#define HLOFF (2 * HBUF + 4096)   // hL: 32 x 65 floats (8320B)

typedef __attribute__((ext_vector_type(8))) short bf16x8;
typedef __attribute__((ext_vector_type(4))) float f32x4;

// ---------------- threefry2x32 (JAX-exact) ----------------
__device__ __forceinline__ void tf2x32(uint32_t k0, uint32_t k1,
                                       uint32_t x0, uint32_t x1,
                                       uint32_t& o0, uint32_t& o1) {
  const uint32_t ks0 = k0, ks1 = k1, ks2 = k0 ^ k1 ^ 0x1BD11BDAu;
  x0 += ks0; x1 += ks1;
  const int rA[4] = {13, 15, 26, 6};
  const int rB[4] = {17, 29, 16, 24};
#pragma unroll
  for (int i = 0; i < 4; ++i) { x0 += x1; x1 = (x1 << rA[i]) | (x1 >> (32 - rA[i])); x1 ^= x0; }
  x0 += ks1; x1 += ks2 + 1u;
#pragma unroll
  for (int i = 0; i < 4; ++i) { x0 += x1; x1 = (x1 << rB[i]) | (x1 >> (32 - rB[i])); x1 ^= x0; }
  x0 += ks2; x1 += ks0 + 2u;
#pragma unroll
  for (int i = 0; i < 4; ++i) { x0 += x1; x1 = (x1 << rA[i]) | (x1 >> (32 - rA[i])); x1 ^= x0; }
  x0 += ks0; x1 += ks1 + 3u;
#pragma unroll
  for (int i = 0; i < 4; ++i) { x0 += x1; x1 = (x1 << rB[i]) | (x1 >> (32 - rB[i])); x1 ^= x0; }
  x0 += ks1; x1 += ks2 + 4u;
#pragma unroll
  for (int i = 0; i < 4; ++i) { x0 += x1; x1 = (x1 << rA[i]) | (x1 >> (32 - rA[i])); x1 ^= x0; }
  o0 = x0 + ks2; o1 = x1 + ks0 + 5u;
}

__device__ __forceinline__ float gumbel_from_bits(uint32_t bits) {
  uint32_t fb = (bits >> 9) | 0x3f800000u;
  float u = __uint_as_float(fb) - 1.0f;
  u = fmaxf(u, 1.17549435e-38f);
  return -logf(-logf(u));
}

__device__ __forceinline__ float sigm(float x) { return 1.0f / (1.0f + __expf(-x)); }
__device__ __forceinline__ float tanh_(float x) {
  float e = __expf(2.0f * x);
  return 1.0f - 2.0f / (e + 1.0f);
}

__device__ __forceinline__ float dot64(const float* __restrict__ w, const float* h) {
  float a = 0.f;
#pragma unroll
  for (int k = 0; k < 64; ++k) a = fmaf(w[k], h[k], a);
  return a;
}

// round-to-bf16 (RNE): returns bits, outputs rounded-back float
__device__ __forceinline__ unsigned short bfbits(float x, float& xf) {
  __hip_bfloat16 hb = __float2bfloat16(x);
  xf = __bfloat162float(hb);
  unsigned short u;
  __builtin_memcpy(&u, &hb, 2);
  return u;
}

// packed RNE f32x2 -> bf16x2 (low = a, high = b); per-element identical to
// __float2bfloat16, so the 3-split stays bit-exact vs the scalar path.
__device__ __forceinline__ uint32_t pkbf(float a, float b) {
  __hip_bfloat162 p = __float22bfloat162_rn(make_float2(a, b));
  uint32_t u; __builtin_memcpy(&u, &p, 4);
  return u;
}
__device__ __forceinline__ float lo16f(uint32_t w) { return __uint_as_float(w << 16); }
__device__ __forceinline__ float hi16f(uint32_t w) { return __uint_as_float(w & 0xffff0000u); }

// LSTM cell epilogue — float expressions identical to r3 (bit-exact path)
__device__ __forceinline__ float lcell(const f32x4 A, const float4 es, float& c) {
  const float gi = A.x + es.x;
  const float gf = A.y + es.y;
  const float gg = A.z + es.z;
  const float go = A.w + es.w;
  const float ci = sigm(gf) * c + sigm(gi) * tanh_(gg);
  c = ci;
  return sigm(go) * tanh_(ci);
}

// Team-of-4 categorical sample + logprob (bit-exact since r3 — do not touch)
template <int N>
__device__ __forceinline__ void samp_team(const float* lg, int g, int C,
                                          uint32_t k0, uint32_t k1, int b,
                                          int& sOut, float& lpOut) {
  float m = -__builtin_inff();
#pragma unroll
  for (int i = 0; i < N; ++i) m = fmaxf(m, lg[i]);
  m = fmaxf(m, __shfl_xor(m, 1));
  m = fmaxf(m, __shfl_xor(m, 2));
  float se = 0.f;
#pragma unroll
  for (int i = 0; i < N; ++i) se += expf(lg[i] - m);
  se += __shfl_xor(se, 1);
  se += __shfl_xor(se, 2);
  const float lse = logf(se);
  float bz = -__builtin_inff(), bl = 0.f;
  int bi = 0x7fffffff;
#pragma unroll
  for (int i = 0; i < N; ++i) {
    const int c = g + 4 * i;
    uint32_t o0, o1; tf2x32(k0, k1, 0u, (uint32_t)(b * C + c), o0, o1);
    const float z = lg[i] + gumbel_from_bits(o0 ^ o1);
    if (z > bz || (z == bz && c < bi)) { bz = z; bi = c; bl = lg[i]; }
  }
#pragma unroll
  for (int d = 1; d <= 2; d <<= 1) {
    const float z2 = __shfl_xor(bz, d);
    const int i2 = __shfl_xor(bi, d);
    const float l2 = __shfl_xor(bl, d);
    if (z2 > bz || (z2 == bz && i2 < bi)) { bz = z2; bi = i2; bl = l2; }
  }
  sOut = bi;
  lpOut = (bl - m) - lse;
}

// ---------------- kernel A: packed precompute (identical to r9) ------------
// Gate-interleaved j' = unit*4 + gate (gate order i,f,g,o; torch j = gate*64+unit)
// embedWi[v][j'] = b_ih[j] + b_hh[j] + sum_k embed[v][k]*W_ih[j][k]   (fp32)
// Wsp[(s*256 + j')*64 + m]: m = kc*32 + q*8 + p holds split_s(W[j][k]) with
//   k = kc*32 + q*8 + cmap(p), cmap(p) = (p>>1) + ((p&1)<<2).
__global__ __launch_bounds__(256) void k_prep(
    const float* __restrict__ embed, const float* __restrict__ W_ih,
    const float* __restrict__ W_hh, const float* __restrict__ b_ih,
    const float* __restrict__ b_hh, float* __restrict__ embedWi,
    unsigned short* __restrict__ Wsp) {
  if (blockIdx.x >= NV) {
    int idx = (blockIdx.x - NV) * 256 + threadIdx.x;  // 0..49151
    int s = idx >> 14;
    int rem = idx & 16383;
    int jp = rem >> 6, m = rem & 63;
    int kc = m >> 5, q = (m >> 3) & 3, p = m & 7;
    int k = kc * 32 + q * 8 + ((p >> 1) + ((p & 1) << 2));
    int j = (jp & 3) * 64 + (jp >> 2);
    float w = W_hh[j * 64 + k];
    float f1, f2, f3;
    unsigned short b1 = bfbits(w, f1);
    unsigned short b2 = bfbits(w - f1, f2);
    unsigned short b3 = bfbits(w - f1 - f2, f3);
    Wsp[idx] = (s == 0) ? b1 : (s == 1) ? b2 : b3;
    return;
  }
  __shared__ float er[64];
  int v = blockIdx.x;
  if (threadIdx.x < 64) er[threadIdx.x] = embed[v * 64 + threadIdx.x];
  __syncthreads();
  int jp = threadIdx.x;
  int j = (jp & 3) * 64 + (jp >> 2);
  float a = b_ih[j] + b_hh[j];
#pragma unroll
  for (int k = 0; k < 64; ++k) a = fmaf(W_ih[j * 64 + k], er[k], a);
  embedWi[v * 256 + jp] = a;
}

// ---------------- kernel B: LSTM + fused heads ----------------------------
// r15: r5's single-wave design was HBM-bound (2.2GB fetch: per-wave Wsp
// re-stream + spill) — reverted to the proven r4 structure (306us, AGPR-
// persistent weights, 2 WG/CU; SGB dropped: measured null). NEW: k_heads is
// fused as a tail — the final h already sits in LDS as split-words; we
// reconstruct it (f1+f2+f3, exact) into hL[32][65] fp32, barrier, and run
// the verbatim head code on threads 0..127 (4-lane teams x 32 rows) reading
// h from LDS. Same float ops, same RNG keys, same b indices -> bit-exact.
// Eliminates: hT materialization (8MB write+read across XCDs), the k_heads
// launch, and its strided global h loads.
// 6 products (drop w2h3, w3h2, w3h3 — all <= 2^-24 rel, fp32-reorder class).
__global__ __launch_bounds__(512, 4) void k_lstm(
    const int* __restrict__ inst0, const int* __restrict__ inst1,
    const float* __restrict__ embedWi, const unsigned short* __restrict__ Wsp,
    const int* __restrict__ canvas0, const int* __restrict__ canvas1,
    const int* __restrict__ ref,
    const float* __restrict__ Wc, const float* __restrict__ bc,
    const float* __restrict__ Ws, const float* __restrict__ bs,
    const float* __restrict__ Wl, const float* __restrict__ bl,
    const float* __restrict__ Wr1, const float* __restrict__ br1,
    const float* __restrict__ Wr2, const float* __restrict__ br2,
    const float* __restrict__ Wp, const float* __restrict__ bp,
    float* __restrict__ out) {
  extern __shared__ char smc[];
  int* idst = (int*)(smc + IDSOFF);    // [t][row] 32x32 ints
  float* hL = (float*)(smc + HLOFF);   // [row][65] final h, padded

  const int tid = threadIdx.x;
  const int lane = tid & 63;
  const int e8 = tid >> 6;        // wave = j'-eighth 0..7
  const int n15 = lane & 15;
  const int quad = lane >> 4;
  const int blk = blockIdx.x;     // 0..1023
  const int rb = (blk & 511) * 32;
  const int* __restrict__ inst = (blk < 512) ? inst0 : inst1;

  // static A-frags: afr[jt][kc][s]; element p = W_s[j'][kc*32+quad*8+cmap(p)]
  bf16x8 afr[2][2][3];
#pragma unroll
  for (int jt = 0; jt < 2; ++jt) {
    const int jrow = (e8 * 2 + jt) * 16 + n15;
#pragma unroll
    for (int kc = 0; kc < 2; ++kc)
#pragma unroll
      for (int s = 0; s < 3; ++s)
        afr[jt][kc][s] =
            *(const bf16x8*)(Wsp + ((s * 256 + jrow) * 64 + kc * 32 + quad * 8));
  }

  for (int i = tid; i < HBUF / 4; i += 512) ((float*)smc)[i] = 0.f;  // zero buf 0

  // pre-stage ALL instruction ids, transposed to [t][row]
  for (int i = tid; i < 1024; i += 512) {
    const int row = i >> 5, tt = i & 31;
    idst[tt * 32 + row] = inst[rb * NSEQ + i];
  }

  float cst[4];   // cells: [jt][rt] -> jt*2+rt
#pragma unroll
  for (int i = 0; i < 4; ++i) cst[i] = 0.f;

  __syncthreads();

#pragma unroll 1
  for (int t = 0; t < NSEQ; ++t) {
    const char* __restrict__ hbr = smc + (t & 1) * HBUF;
    char* __restrict__ hbw = smc + ((t & 1) ^ 1) * HBUF;

    // ids + es gathers (both rt up front; latency hidden under block 1)
    const int v0 = idst[t * 32 + n15];
    const int vn = idst[t * 32 + 16 + n15];
    float4 esc[2], esn[2];
#pragma unroll
    for (int jt = 0; jt < 2; ++jt) {
      esc[jt] = *(const float4*)(embedWi + v0 * 256 + (e8 * 8 + jt * 4 + quad) * 4);
      esn[jt] = *(const float4*)(embedWi + vn * 256 + (e8 * 8 + jt * 4 + quad) * 4);
    }

    // B-frags rt0 and rt1 (reads precede all LDS writes this timestep)
    bf16x8 b0[2][3], b1[2][3];
#pragma unroll
    for (int kc = 0; kc < 2; ++kc)
#pragma unroll
      for (int s = 0; s < 3; ++s) {
        b0[kc][s] = *(const bf16x8*)(hbr + s * SPL + 0 * RTG +
                                     (kc * 4 + quad) * CHK + n15 * 16);
        b1[kc][s] = *(const bf16x8*)(hbr + s * SPL + 1 * RTG +
                                     (kc * 4 + quad) * CHK + n15 * 16);
      }

    // ---- a00 (jt0,rt0), 12-MFMA chain (order identical to r3) ----
    f32x4 a00 = (f32x4){0.f, 0.f, 0.f, 0.f};
#pragma unroll
    for (int kc = 0; kc < 2; ++kc) {
      a00 = __builtin_amdgcn_mfma_f32_16x16x32_bf16(afr[0][kc][0], b0[kc][2], a00, 0, 0, 0);
      a00 = __builtin_amdgcn_mfma_f32_16x16x32_bf16(afr[0][kc][2], b0[kc][0], a00, 0, 0, 0);
      a00 = __builtin_amdgcn_mfma_f32_16x16x32_bf16(afr[0][kc][1], b0[kc][1], a00, 0, 0, 0);
      a00 = __builtin_amdgcn_mfma_f32_16x16x32_bf16(afr[0][kc][0], b0[kc][1], a00, 0, 0, 0);
      a00 = __builtin_amdgcn_mfma_f32_16x16x32_bf16(afr[0][kc][1], b0[kc][0], a00, 0, 0, 0);
      a00 = __builtin_amdgcn_mfma_f32_16x16x32_bf16(afr[0][kc][0], b0[kc][0], a00, 0, 0, 0);
    }

    // ---- a01 (jt1,rt0) ----
    f32x4 a01 = (f32x4){0.f, 0.f, 0.f, 0.f};
#pragma unroll
    for (int kc = 0; kc < 2; ++kc) {
      a01 = __builtin_amdgcn_mfma_f32_16x16x32_bf16(afr[1][kc][0], b0[kc][2], a01, 0, 0, 0);
      a01 = __builtin_amdgcn_mfma_f32_16x16x32_bf16(afr[1][kc][2], b0[kc][0], a01, 0, 0, 0);
      a01 = __builtin_amdgcn_mfma_f32_16x16x32_bf16(afr[1][kc][1], b0[kc][1], a01, 0, 0, 0);
      a01 = __builtin_amdgcn_mfma_f32_16x16x32_bf16(afr[1][kc][0], b0[kc][1], a01, 0, 0, 0);
      a01 = __builtin_amdgcn_mfma_f32_16x16x32_bf16(afr[1][kc][1], b0[kc][0], a01, 0, 0, 0);
      a01 = __builtin_amdgcn_mfma_f32_16x16x32_bf16(afr[1][kc][0], b0[kc][0], a01, 0, 0, 0);
    }
    const float hv00 = lcell(a00, esc[0], cst[0]);

    // ---- a10 (jt0,rt1) ----
    f32x4 a10 = (f32x4){0.f, 0.f, 0.f, 0.f};
#pragma unroll
    for (int kc = 0; kc < 2; ++kc) {
      a10 = __builtin_amdgcn_mfma_f32_16x16x32_bf16(afr[0][kc][0], b1[kc][2], a10, 0, 0, 0);
      a10 = __builtin_amdgcn_mfma_f32_16x16x32_bf16(afr[0][kc][2], b1[kc][0], a10, 0, 0, 0);
      a10 = __builtin_amdgcn_mfma_f32_16x16x32_bf16(afr[0][kc][1], b1[kc][1], a10, 0, 0, 0);
      a10 = __builtin_amdgcn_mfma_f32_16x16x32_bf16(afr[0][kc][0], b1[kc][1], a10, 0, 0, 0);
      a10 = __builtin_amdgcn_mfma_f32_16x16x32_bf16(afr[0][kc][1], b1[kc][0], a10, 0, 0, 0);
      a10 = __builtin_amdgcn_mfma_f32_16x16x32_bf16(afr[0][kc][0], b1[kc][0], a10, 0, 0, 0);
    }
    const float hv10 = lcell(a01, esc[1], cst[2]);
    {
      const uint32_t w1 = pkbf(hv00, hv10);
      float d0 = hv00 - lo16f(w1), d1 = hv10 - hi16f(w1);
      const uint32_t w2 = pkbf(d0, d1);
      d0 -= lo16f(w2); d1 -= hi16f(w2);
      const uint32_t w3 = pkbf(d0, d1);
      char* base = hbw + 0 * RTG + e8 * CHK + n15 * 16 + quad * 4;
      *(uint32_t*)(base + 0 * SPL) = w1;
      *(uint32_t*)(base + 1 * SPL) = w2;
      *(uint32_t*)(base + 2 * SPL) = w3;
    }

    // ---- a11 (jt1,rt1) ----
    f32x4 a11 = (f32x4){0.f, 0.f, 0.f, 0.f};
#pragma unroll
    for (int kc = 0; kc < 2; ++kc) {
      a11 = __builtin_amdgcn_mfma_f32_16x16x32_bf16(afr[1][kc][0], b1[kc][2], a11, 0, 0, 0);
      a11 = __builtin_amdgcn_mfma_f32_16x16x32_bf16(afr[1][kc][2], b1[kc][0], a11, 0, 0, 0);
      a11 = __builtin_amdgcn_mfma_f32_16x16x32_bf16(afr[1][kc][1], b1[kc][1], a11, 0, 0, 0);
      a11 = __builtin_amdgcn_mfma_f32_16x16x32_bf16(afr[1][kc][0], b1[kc][1], a11, 0, 0, 0);
      a11 = __builtin_amdgcn_mfma_f32_16x16x32_bf16(afr[1][kc][1], b1[kc][0], a11, 0, 0, 0);
      a11 = __builtin_amdgcn_mfma_f32_16x16x32_bf16(afr[1][kc][0], b1[kc][0], a11, 0, 0, 0);
    }
    const float hv01 = lcell(a10, esn[0], cst[1]);

    const float hv11 = lcell(a11, esn[1], cst[3]);
    {
      const uint32_t w1 = pkbf(hv01, hv11);
      float d0 = hv01 - lo16f(w1), d1 = hv11 - hi16f(w1);
      const uint32_t w2 = pkbf(d0, d1);
      d0 -= lo16f(w2); d1 -= hi16f(w2);
      const uint32_t w3 = pkbf(d0, d1);
      char* base = hbw + 1 * RTG + e8 * CHK + n15 * 16 + quad * 4;
      *(uint32_t*)(base + 0 * SPL) = w1;
      *(uint32_t*)(base + 1 * SPL) = w2;
      *(uint32_t*)(base + 2 * SPL) = w3;
    }

    __syncthreads();
  }

  // ---- reconstruct final h (buf0) into hL[row][65]; exact: f1+f2+f3 ----
#pragma unroll
  for (int rt = 0; rt < 2; ++rt) {
    const char* base = smc + rt * RTG + e8 * CHK + n15 * 16 + quad * 4;
    const uint32_t w1 = *(const uint32_t*)(base + 0 * SPL);
    const uint32_t w2 = *(const uint32_t*)(base + 1 * SPL);
    const uint32_t w3 = *(const uint32_t*)(base + 2 * SPL);
    const float hv0 = lo16f(w1) + lo16f(w2) + lo16f(w3);
    const float hv1 = hi16f(w1) + hi16f(w2) + hi16f(w3);
    const int row = rt * 16 + n15;
    hL[row * 65 + e8 * 8 + 0 + quad] = hv0;
    hL[row * 65 + e8 * 8 + 4 + quad] = hv1;
  }
  __syncthreads();

  // ---- fused heads tail: threads 0..127 = 32 rows x 4-lane teams ----
  if (tid >= 128) return;
  const int g = tid & 3;
  const int r = tid >> 2;         // 0..31
  const int b = rb + r;           // global batch row
  const float NEG = -__builtin_inff();

  uint32_t kk0[7], kk1[7];
#pragma unroll
  for (int i = 0; i < 7; ++i) {
    uint32_t o0, o1; tf2x32(0u, 42u, 0u, (uint32_t)i, o0, o1);
    kk0[i] = o0; kk1[i] = o1;
  }

  float h[64];
#pragma unroll
  for (int u = 0; u < 64; ++u) h[u] = hL[r * 65 + u];

  float lgc[1], lgs[1];
  lgc[0] = (g < 3) ? (bc[g] + dot64(Wc + g * 64, h)) : NEG;
  lgs[0] = (g < 3) ? (bs[g] + dot64(Ws + g * 64, h)) : NEG;

  if (blk < 512) {   // s = 0
    int cs0, ss0, loc0; float clp0, slp0, llp0;
    samp_team<1>(lgc, g, 3, kk0[0], kk1[0], b, cs0, clp0);
    samp_team<1>(lgs, g, 3, kk0[1], kk1[1], b, ss0, slp0);
    float lgl[7];
#pragma unroll
    for (int i = 0; i < 7; ++i) {
      const int cc = g + 4 * i;
      lgl[i] = (cc < 25) ? (bl[cc] + dot64(Wl + cc * 64, h)) : NEG;
    }
    samp_team<7>(lgl, g, 25, kk0[2], kk1[2], b, loc0, llp0);

    if (g == 0) {
      const int p0 = min(max(loc0, 0), 24);
      const int4 pt = ((const int4*)(canvas1 + b * 100))[p0];
      const bool ok0 = (loc0 >= 0) && (loc0 < 25) && (pt.x + pt.y + pt.z + pt.w >= 0);
      const float loc_r0 = ok0 ? 1.f : -1.f;
      const float col_r0 = ok0 ? ((cs0 == pt.x) ? 1.f : -1.f) : 0.f;
      out[0 * NB + b] = clp0;
      out[1 * NB + b] = slp0;
      out[2 * NB + b] = llp0;
      out[7 * NB + b] = loc_r0;
      out[8 * NB + b] = col_r0;
      out[9 * NB + b] = loc_r0;
    }
  } else {           // s = 1
    int cs1, ss1, ls1; float clp1, slp1, llp1;
    samp_team<1>(lgc, g, 3, kk0[3], kk1[3], b, cs1, clp1);
    samp_team<1>(lgs, g, 3, kk0[4], kk1[4], b, ss1, slp1);
    float lgp[2];
#pragma unroll
    for (int i = 0; i < 2; ++i) {
      const int cc = g + 4 * i;
      lgp[i] = bp[cc] + dot64(Wp + cc * 64, h);
    }
    samp_team<2>(lgp, g, 8, kk0[5], kk1[5], b, ls1, llp1);

    float uv8[8], w64[8], w65[8], w66[8], w67[8], wr2[8];
#pragma unroll
    for (int i = 0; i < 8; ++i) {
      const int j = g + 4 * i;
      uv8[i] = br1[j] + dot64(Wr1 + j * 68, h);
      const float* wr = Wr1 + j * 68 + 64;
      w64[i] = wr[0]; w65[i] = wr[1]; w66[i] = wr[2]; w67[i] = wr[3];
      wr2[i] = Wr2[j];
    }
    float lgA[7];
#pragma unroll
    for (int i = 0; i < 7; ++i) lgA[i] = NEG;
    const float b2 = br2[0];
#pragma unroll
    for (int p = 0; p < 25; ++p) {
      const int4 c4 = ((const int4*)(canvas0 + b * 100))[p];
      const float f0 = (float)c4.x, f1 = (float)c4.y;
      const float f2 = (float)c4.z, f3 = (float)c4.w;
      float part = 0.f;
#pragma unroll
      for (int i = 0; i < 8; ++i) {
        float hj = uv8[i];
        hj = fmaf(w64[i], f0, hj);
        hj = fmaf(w65[i], f1, hj);
        hj = fmaf(w66[i], f2, hj);
        hj = fmaf(w67[i], f3, hj);
        part = fmaf(wr2[i], fmaxf(hj, 0.f), part);
      }
      part += __shfl_xor(part, 1);
      part += __shfl_xor(part, 2);
      const float ap = b2 + part;
      if ((p & 3) == g) lgA[p >> 2] = ap;
    }
    int att_s; float alp1;
    samp_team<7>(lgA, g, 25, kk0[6], kk1[6], b, att_s, alp1);

    if (g == 0) {
      const int4 r4 = ((const int4*)(canvas0 + b * 100))[att_s];
      const int4 rr = *(const int4*)(ref + b * 4);
      const bool match = (r4.x == rr.x) && (r4.y == rr.y) &&
                         (r4.z == rr.z) && (r4.w == rr.w);
      const float att_reward = match ? 1.f : -1.f;
      const int ox = (int)((0x22001120u >> (ls1 * 4)) & 0xFu) - 1;
      const int oy = (int)((0x20200211u >> (ls1 * 4)) & 0xFu) - 1;
      const int loc1 = (r4.z + ox) * 5 + (r4.w + oy);
      const int p1 = min(max(loc1, 0), 24);
      const int4 q4 = ((const int4*)(canvas1 + b * 100))[p1];
      const bool ok1 = (loc1 >= 0) && (loc1 < 25) && (q4.x + q4.y + q4.z + q4.w >= 0);
      const float loc_r1 = ok1 ? 1.f : -1.f;
      const float col_r1 = ok1 ? ((cs1 == q4.x) ? 1.f : -1.f) : 0.f;
      out[3 * NB + b]  = clp1;
      out[4 * NB + b]  = slp1;
      out[5 * NB + b]  = llp1;
      out[6 * NB + b]  = alp1;
      out[10 * NB + b] = loc_r1;
      out[11 * NB + b] = col_r1;
      out[12 * NB + b] = loc_r1;
      out[13 * NB + b] = att_reward;
    }
  }
}

extern "C" void kernel_launch(void* const* d_in, const int* in_sizes, int n_in,
                              void* d_out, int out_size, void* d_ws, size_t ws_size,
                              hipStream_t stream) {
  const int* inst0 = (const int*)d_in[0];
  const int* inst1 = (const int*)d_in[1];
  const int* canvas0 = (const int*)d_in[2];
  const int* canvas1 = (const int*)d_in[3];
  const int* ref = (const int*)d_in[4];
  const float* embed = (const float*)d_in[5];
  const float* W_ih = (const float*)d_in[6];
  const float* W_hh = (const float*)d_in[7];
  const float* b_ih = (const float*)d_in[8];
  const float* b_hh = (const float*)d_in[9];
  const float* Wc = (const float*)d_in[10];
  const float* bc = (const float*)d_in[11];
  const float* Ws = (const float*)d_in[12];
  const float* bs = (const float*)d_in[13];
  const float* Wl = (const float*)d_in[14];
  const float* bl = (const float*)d_in[15];
  const float* Wr1 = (const float*)d_in[16];
  const float* br1 = (const float*)d_in[17];
  const float* Wr2 = (const float*)d_in[18];
  const float* br2 = (const float*)d_in[19];
  const float* Wp = (const float*)d_in[20];
  const float* bp = (const float*)d_in[21];

  float* ws = (float*)d_ws;
  float* embedWi = ws;                               // 1001*256 fp32
  unsigned short* Wsp = (unsigned short*)(ws + NV * 256);  // 3*256*64 bf16
  float* out = (float*)d_out;

  const size_t ldsBytes = HLOFF + 32 * 65 * 4;  // h dbuf + idst + hL = 38528
  k_prep<<<NV + 192, 256, 0, stream>>>(embed, W_ih, W_hh, b_ih, b_hh, embedWi, Wsp);
  k_lstm<<<1024, 512, ldsBytes, stream>>>(inst0, inst1, embedWi, Wsp,
                                          canvas0, canvas1, ref,
                                          Wc, bc, Ws, bs, Wl, bl,
                                          Wr1, br1, Wr2, br2, Wp, bp, out);
}

// Round 7
// 456.475 us; speedup vs baseline: 2.1147x; 1.0732x over previous
//
#include <hip/hip_runtime.h>
#include <hip/hip_bf16.h>
#include <stdint.h>
#include <math.h>

#define NB 16384      // batch
#define NSEQ 32       // sequence length
#define NV 1001       // vocab (V+1)
#define NROWS 32768   // 2 * NB flattened rows

// LDS h-buffer geometry (bytes), R=32 rows per WG
#define CHK 272           // chunk stride (16 rows x 16B + 16B pad)
#define RTG (8 * CHK)     // 2176: row-tile-group stride (8 k-chunks)
#define SPL (2 * RTG)     // 4352: split stride (2 row-tile-groups)
#define HBUF (3 * SPL)    // 13056: one h buffer (3 splits)
#define IDSOFF (2 * HBUF)         // idst: 32x32 ints (4KB)
#define HLOFF (2 * HBUF + 4096)   // hL: 32 x 68 floats (8704B, 16B-aligned rows)

typedef __attribute__((ext_vector_type(8))) short bf16x8;
typedef __attribute__((ext_vector_type(4))) float f32x4;

// ---------------- threefry2x32 (JAX-exact) ----------------
__device__ __forceinline__ void tf2x32(uint32_t k0, uint32_t k1,
                                       uint32_t x0, uint32_t x1,
                                       uint32_t& o0, uint32_t& o1) {
  const uint32_t ks0 = k0, ks1 = k1, ks2 = k0 ^ k1 ^ 0x1BD11BDAu;
  x0 += ks0; x1 += ks1;
  const int rA[4] = {13, 15, 26, 6};
  const int rB[4] = {17, 29, 16, 24};
#pragma unroll
  for (int i = 0; i < 4; ++i) { x0 += x1; x1 = (x1 << rA[i]) | (x1 >> (32 - rA[i])); x1 ^= x0; }
  x0 += ks1; x1 += ks2 + 1u;
#pragma unroll
  for (int i = 0; i < 4; ++i) { x0 += x1; x1 = (x1 << rB[i]) | (x1 >> (32 - rB[i])); x1 ^= x0; }
  x0 += ks2; x1 += ks0 + 2u;
#pragma unroll
  for (int i = 0; i < 4; ++i) { x0 += x1; x1 = (x1 << rA[i]) | (x1 >> (32 - rA[i])); x1 ^= x0; }
  x0 += ks0; x1 += ks1 + 3u;
#pragma unroll
  for (int i = 0; i < 4; ++i) { x0 += x1; x1 = (x1 << rB[i]) | (x1 >> (32 - rB[i])); x1 ^= x0; }
  x0 += ks1; x1 += ks2 + 4u;
#pragma unroll
  for (int i = 0; i < 4; ++i) { x0 += x1; x1 = (x1 << rA[i]) | (x1 >> (32 - rA[i])); x1 ^= x0; }
  o0 = x0 + ks2; o1 = x1 + ks0 + 5u;
}

__device__ __forceinline__ float gumbel_from_bits(uint32_t bits) {
  uint32_t fb = (bits >> 9) | 0x3f800000u;
  float u = __uint_as_float(fb) - 1.0f;
  u = fmaxf(u, 1.17549435e-38f);
  return -logf(-logf(u));
}

__device__ __forceinline__ float sigm(float x) { return 1.0f / (1.0f + __expf(-x)); }
__device__ __forceinline__ float tanh_(float x) {
  float e = __expf(2.0f * x);
  return 1.0f - 2.0f / (e + 1.0f);
}

// dot over 64 elements; h may live in LDS (broadcast within 4-lane team)
__device__ __forceinline__ float dot64(const float* __restrict__ w, const float* h) {
  float a = 0.f;
#pragma unroll
  for (int k = 0; k < 64; ++k) a = fmaf(w[k], h[k], a);
  return a;
}

// round-to-bf16 (RNE): returns bits, outputs rounded-back float
__device__ __forceinline__ unsigned short bfbits(float x, float& xf) {
  __hip_bfloat16 hb = __float2bfloat16(x);
  xf = __bfloat162float(hb);
  unsigned short u;
  __builtin_memcpy(&u, &hb, 2);
  return u;
}

// packed RNE f32x2 -> bf16x2 (low = a, high = b); per-element identical to
// __float2bfloat16, so the 3-split stays bit-exact vs the scalar path.
__device__ __forceinline__ uint32_t pkbf(float a, float b) {
  __hip_bfloat162 p = __float22bfloat162_rn(make_float2(a, b));
  uint32_t u; __builtin_memcpy(&u, &p, 4);
  return u;
}
__device__ __forceinline__ float lo16f(uint32_t w) { return __uint_as_float(w << 16); }
__device__ __forceinline__ float hi16f(uint32_t w) { return __uint_as_float(w & 0xffff0000u); }

// LSTM cell epilogue — float expressions identical to r3 (bit-exact path)
__device__ __forceinline__ float lcell(const f32x4 A, const float4 es, float& c) {
  const float gi = A.x + es.x;
  const float gf = A.y + es.y;
  const float gg = A.z + es.z;
  const float go = A.w + es.w;
  const float ci = sigm(gf) * c + sigm(gi) * tanh_(gg);
  c = ci;
  return sigm(go) * tanh_(ci);
}

// Team-of-4 categorical sample + logprob (bit-exact since r3 — do not touch)
template <int N>
__device__ __forceinline__ void samp_team(const float* lg, int g, int C,
                                          uint32_t k0, uint32_t k1, int b,
                                          int& sOut, float& lpOut) {
  float m = -__builtin_inff();
#pragma unroll
  for (int i = 0; i < N; ++i) m = fmaxf(m, lg[i]);
  m = fmaxf(m, __shfl_xor(m, 1));
  m = fmaxf(m, __shfl_xor(m, 2));
  float se = 0.f;
#pragma unroll
  for (int i = 0; i < N; ++i) se += expf(lg[i] - m);
  se += __shfl_xor(se, 1);
  se += __shfl_xor(se, 2);
  const float lse = logf(se);
  float bz = -__builtin_inff(), bl = 0.f;
  int bi = 0x7fffffff;
#pragma unroll
  for (int i = 0; i < N; ++i) {
    const int c = g + 4 * i;
    uint32_t o0, o1; tf2x32(k0, k1, 0u, (uint32_t)(b * C + c), o0, o1);
    const float z = lg[i] + gumbel_from_bits(o0 ^ o1);
    if (z > bz || (z == bz && c < bi)) { bz = z; bi = c; bl = lg[i]; }
  }
#pragma unroll
  for (int d = 1; d <= 2; d <<= 1) {
    const float z2 = __shfl_xor(bz, d);
    const int i2 = __shfl_xor(bi, d);
    const float l2 = __shfl_xor(bl, d);
    if (z2 > bz || (z2 == bz && i2 < bi)) { bz = z2; bi = i2; bl = l2; }
  }
  sOut = bi;
  lpOut = (bl - m) - lse;
}

// ---------------- kernel A: packed precompute (identical to r9) ------------
// Gate-interleaved j' = unit*4 + gate (gate order i,f,g,o; torch j = gate*64+unit)
// embedWi[v][j'] = b_ih[j] + b_hh[j] + sum_k embed[v][k]*W_ih[j][k]   (fp32)
// Wsp[(s*256 + j')*64 + m]: m = kc*32 + q*8 + p holds split_s(W[j][k]) with
//   k = kc*32 + q*8 + cmap(p), cmap(p) = (p>>1) + ((p&1)<<2).
__global__ __launch_bounds__(256) void k_prep(
    const float* __restrict__ embed, const float* __restrict__ W_ih,
    const float* __restrict__ W_hh, const float* __restrict__ b_ih,
    const float* __restrict__ b_hh, float* __restrict__ embedWi,
    unsigned short* __restrict__ Wsp) {
  if (blockIdx.x >= NV) {
    int idx = (blockIdx.x - NV) * 256 + threadIdx.x;  // 0..49151
    int s = idx >> 14;
    int rem = idx & 16383;
    int jp = rem >> 6, m = rem & 63;
    int kc = m >> 5, q = (m >> 3) & 3, p = m & 7;
    int k = kc * 32 + q * 8 + ((p >> 1) + ((p & 1) << 2));
    int j = (jp & 3) * 64 + (jp >> 2);
    float w = W_hh[j * 64 + k];
    float f1, f2, f3;
    unsigned short b1 = bfbits(w, f1);
    unsigned short b2 = bfbits(w - f1, f2);
    unsigned short b3 = bfbits(w - f1 - f2, f3);
    Wsp[idx] = (s == 0) ? b1 : (s == 1) ? b2 : b3;
    return;
  }
  __shared__ float er[64];
  int v = blockIdx.x;
  if (threadIdx.x < 64) er[threadIdx.x] = embed[v * 64 + threadIdx.x];
  __syncthreads();
  int jp = threadIdx.x;
  int j = (jp & 3) * 64 + (jp >> 2);
  float a = b_ih[j] + b_hh[j];
#pragma unroll
  for (int k = 0; k < 64; ++k) a = fmaf(W_ih[j * 64 + k], er[k], a);
  embedWi[v * 256 + jp] = a;
}

// ---------------- kernel B: LSTM + fused heads (spill-free tail) ----------
// r16: r6's fusion was right (non-lstm overhead 117->64us) but the tail's
// h[64]+weights register set (~140 live) blew the (512,4) 128-reg budget ->
// full scratch spill (WRITE 118MB, FETCH +77MB, k_lstm 306->425). r16 keeps
// the fusion and reads h IN PLACE from LDS: hL re-padded to 68-float rows
// (272B, 16B-aligned -> ds_read_b128; team lanes broadcast same address).
// Tail live set ~60 regs -> no spill. Float ops / RNG / indices unchanged.
// Main loop identical to r4-minus-SGB (proven 306us structure).
// 6 products (drop w2h3, w3h2, w3h3 — all <= 2^-24 rel, fp32-reorder class).
__global__ __launch_bounds__(512, 4) void k_lstm(
    const int* __restrict__ inst0, const int* __restrict__ inst1,
    const float* __restrict__ embedWi, const unsigned short* __restrict__ Wsp,
    const int* __restrict__ canvas0, const int* __restrict__ canvas1,
    const int* __restrict__ ref,
    const float* __restrict__ Wc, const float* __restrict__ bc,
    const float* __restrict__ Ws, const float* __restrict__ bs,
    const float* __restrict__ Wl, const float* __restrict__ bl,
    const float* __restrict__ Wr1, const float* __restrict__ br1,
    const float* __restrict__ Wr2, const float* __restrict__ br2,
    const float* __restrict__ Wp, const float* __restrict__ bp,
    float* __restrict__ out) {
  extern __shared__ char smc[];
  int* idst = (int*)(smc + IDSOFF);    // [t][row] 32x32 ints
  float* hL = (float*)(smc + HLOFF);   // [row][68] final h, 16B-aligned rows

  const int tid = threadIdx.x;
  const int lane = tid & 63;
  const int e8 = tid >> 6;        // wave = j'-eighth 0..7
  const int n15 = lane & 15;
  const int quad = lane >> 4;
  const int blk = blockIdx.x;     // 0..1023
  const int rb = (blk & 511) * 32;
  const int* __restrict__ inst = (blk < 512) ? inst0 : inst1;

  // static A-frags: afr[jt][kc][s]; element p = W_s[j'][kc*32+quad*8+cmap(p)]
  bf16x8 afr[2][2][3];
#pragma unroll
  for (int jt = 0; jt < 2; ++jt) {
    const int jrow = (e8 * 2 + jt) * 16 + n15;
#pragma unroll
    for (int kc = 0; kc < 2; ++kc)
#pragma unroll
      for (int s = 0; s < 3; ++s)
        afr[jt][kc][s] =
            *(const bf16x8*)(Wsp + ((s * 256 + jrow) * 64 + kc * 32 + quad * 8));
  }

  for (int i = tid; i < HBUF / 4; i += 512) ((float*)smc)[i] = 0.f;  // zero buf 0

  // pre-stage ALL instruction ids, transposed to [t][row]
  for (int i = tid; i < 1024; i += 512) {
    const int row = i >> 5, tt = i & 31;
    idst[tt * 32 + row] = inst[rb * NSEQ + i];
  }

  float cst[4];   // cells: [jt][rt] -> jt*2+rt
#pragma unroll
  for (int i = 0; i < 4; ++i) cst[i] = 0.f;

  __syncthreads();

#pragma unroll 1
  for (int t = 0; t < NSEQ; ++t) {
    const char* __restrict__ hbr = smc + (t & 1) * HBUF;
    char* __restrict__ hbw = smc + ((t & 1) ^ 1) * HBUF;

    // ids + es gathers (both rt up front; latency hidden under block 1)
    const int v0 = idst[t * 32 + n15];
    const int vn = idst[t * 32 + 16 + n15];
    float4 esc[2], esn[2];
#pragma unroll
    for (int jt = 0; jt < 2; ++jt) {
      esc[jt] = *(const float4*)(embedWi + v0 * 256 + (e8 * 8 + jt * 4 + quad) * 4);
      esn[jt] = *(const float4*)(embedWi + vn * 256 + (e8 * 8 + jt * 4 + quad) * 4);
    }

    // B-frags rt0 and rt1 (reads precede all LDS writes this timestep)
    bf16x8 b0[2][3], b1[2][3];
#pragma unroll
    for (int kc = 0; kc < 2; ++kc)
#pragma unroll
      for (int s = 0; s < 3; ++s) {
        b0[kc][s] = *(const bf16x8*)(hbr + s * SPL + 0 * RTG +
                                     (kc * 4 + quad) * CHK + n15 * 16);
        b1[kc][s] = *(const bf16x8*)(hbr + s * SPL + 1 * RTG +
                                     (kc * 4 + quad) * CHK + n15 * 16);
      }

    // ---- a00 (jt0,rt0), 12-MFMA chain (order identical to r3) ----
    f32x4 a00 = (f32x4){0.f, 0.f, 0.f, 0.f};
#pragma unroll
    for (int kc = 0; kc < 2; ++kc) {
      a00 = __builtin_amdgcn_mfma_f32_16x16x32_bf16(afr[0][kc][0], b0[kc][2], a00, 0, 0, 0);
      a00 = __builtin_amdgcn_mfma_f32_16x16x32_bf16(afr[0][kc][2], b0[kc][0], a00, 0, 0, 0);
      a00 = __builtin_amdgcn_mfma_f32_16x16x32_bf16(afr[0][kc][1], b0[kc][1], a00, 0, 0, 0);
      a00 = __builtin_amdgcn_mfma_f32_16x16x32_bf16(afr[0][kc][0], b0[kc][1], a00, 0, 0, 0);
      a00 = __builtin_amdgcn_mfma_f32_16x16x32_bf16(afr[0][kc][1], b0[kc][0], a00, 0, 0, 0);
      a00 = __builtin_amdgcn_mfma_f32_16x16x32_bf16(afr[0][kc][0], b0[kc][0], a00, 0, 0, 0);
    }

    // ---- a01 (jt1,rt0) ----
    f32x4 a01 = (f32x4){0.f, 0.f, 0.f, 0.f};
#pragma unroll
    for (int kc = 0; kc < 2; ++kc) {
      a01 = __builtin_amdgcn_mfma_f32_16x16x32_bf16(afr[1][kc][0], b0[kc][2], a01, 0, 0, 0);
      a01 = __builtin_amdgcn_mfma_f32_16x16x32_bf16(afr[1][kc][2], b0[kc][0], a01, 0, 0, 0);
      a01 = __builtin_amdgcn_mfma_f32_16x16x32_bf16(afr[1][kc][1], b0[kc][1], a01, 0, 0, 0);
      a01 = __builtin_amdgcn_mfma_f32_16x16x32_bf16(afr[1][kc][0], b0[kc][1], a01, 0, 0, 0);
      a01 = __builtin_amdgcn_mfma_f32_16x16x32_bf16(afr[1][kc][1], b0[kc][0], a01, 0, 0, 0);
      a01 = __builtin_amdgcn_mfma_f32_16x16x32_bf16(afr[1][kc][0], b0[kc][0], a01, 0, 0, 0);
    }
    const float hv00 = lcell(a00, esc[0], cst[0]);

    // ---- a10 (jt0,rt1) ----
    f32x4 a10 = (f32x4){0.f, 0.f, 0.f, 0.f};
#pragma unroll
    for (int kc = 0; kc < 2; ++kc) {
      a10 = __builtin_amdgcn_mfma_f32_16x16x32_bf16(afr[0][kc][0], b1[kc][2], a10, 0, 0, 0);
      a10 = __builtin_amdgcn_mfma_f32_16x16x32_bf16(afr[0][kc][2], b1[kc][0], a10, 0, 0, 0);
      a10 = __builtin_amdgcn_mfma_f32_16x16x32_bf16(afr[0][kc][1], b1[kc][1], a10, 0, 0, 0);
      a10 = __builtin_amdgcn_mfma_f32_16x16x32_bf16(afr[0][kc][0], b1[kc][1], a10, 0, 0, 0);
      a10 = __builtin_amdgcn_mfma_f32_16x16x32_bf16(afr[0][kc][1], b1[kc][0], a10, 0, 0, 0);
      a10 = __builtin_amdgcn_mfma_f32_16x16x32_bf16(afr[0][kc][0], b1[kc][0], a10, 0, 0, 0);
    }
    const float hv10 = lcell(a01, esc[1], cst[2]);
    {
      const uint32_t w1 = pkbf(hv00, hv10);
      float d0 = hv00 - lo16f(w1), d1 = hv10 - hi16f(w1);
      const uint32_t w2 = pkbf(d0, d1);
      d0 -= lo16f(w2); d1 -= hi16f(w2);
      const uint32_t w3 = pkbf(d0, d1);
      char* base = hbw + 0 * RTG + e8 * CHK + n15 * 16 + quad * 4;
      *(uint32_t*)(base + 0 * SPL) = w1;
      *(uint32_t*)(base + 1 * SPL) = w2;
      *(uint32_t*)(base + 2 * SPL) = w3;
    }

    // ---- a11 (jt1,rt1) ----
    f32x4 a11 = (f32x4){0.f, 0.f, 0.f, 0.f};
#pragma unroll
    for (int kc = 0; kc < 2; ++kc) {
      a11 = __builtin_amdgcn_mfma_f32_16x16x32_bf16(afr[1][kc][0], b1[kc][2], a11, 0, 0, 0);
      a11 = __builtin_amdgcn_mfma_f32_16x16x32_bf16(afr[1][kc][2], b1[kc][0], a11, 0, 0, 0);
      a11 = __builtin_amdgcn_mfma_f32_16x16x32_bf16(afr[1][kc][1], b1[kc][1], a11, 0, 0, 0);
      a11 = __builtin_amdgcn_mfma_f32_16x16x32_bf16(afr[1][kc][0], b1[kc][1], a11, 0, 0, 0);
      a11 = __builtin_amdgcn_mfma_f32_16x16x32_bf16(afr[1][kc][1], b1[kc][0], a11, 0, 0, 0);
      a11 = __builtin_amdgcn_mfma_f32_16x16x32_bf16(afr[1][kc][0], b1[kc][0], a11, 0, 0, 0);
    }
    const float hv01 = lcell(a10, esn[0], cst[1]);

    const float hv11 = lcell(a11, esn[1], cst[3]);
    {
      const uint32_t w1 = pkbf(hv01, hv11);
      float d0 = hv01 - lo16f(w1), d1 = hv11 - hi16f(w1);
      const uint32_t w2 = pkbf(d0, d1);
      d0 -= lo16f(w2); d1 -= hi16f(w2);
      const uint32_t w3 = pkbf(d0, d1);
      char* base = hbw + 1 * RTG + e8 * CHK + n15 * 16 + quad * 4;
      *(uint32_t*)(base + 0 * SPL) = w1;
      *(uint32_t*)(base + 1 * SPL) = w2;
      *(uint32_t*)(base + 2 * SPL) = w3;
    }

    __syncthreads();
  }

  // ---- reconstruct final h (buf0) into hL[row][68]; exact: f1+f2+f3 ----
#pragma unroll
  for (int rt = 0; rt < 2; ++rt) {
    const char* base = smc + rt * RTG + e8 * CHK + n15 * 16 + quad * 4;
    const uint32_t w1 = *(const uint32_t*)(base + 0 * SPL);
    const uint32_t w2 = *(const uint32_t*)(base + 1 * SPL);
    const uint32_t w3 = *(const uint32_t*)(base + 2 * SPL);
    const float hv0 = lo16f(w1) + lo16f(w2) + lo16f(w3);
    const float hv1 = hi16f(w1) + hi16f(w2) + hi16f(w3);
    const int row = rt * 16 + n15;
    hL[row * 68 + e8 * 8 + 0 + quad] = hv0;
    hL[row * 68 + e8 * 8 + 4 + quad] = hv1;
  }
  __syncthreads();

  // ---- fused heads tail: threads 0..127 = 32 rows x 4-lane teams ----
  // h stays in LDS (broadcast reads) — tail live set ~60 regs, no spill.
  if (tid >= 128) return;
  const int g = tid & 3;
  const int r = tid >> 2;         // 0..31
  const int b = rb + r;           // global batch row
  const float* __restrict__ h = hL + r * 68;
  const float NEG = -__builtin_inff();

  uint32_t kk0[7], kk1[7];
#pragma unroll
  for (int i = 0; i < 7; ++i) {
    uint32_t o0, o1; tf2x32(0u, 42u, 0u, (uint32_t)i, o0, o1);
    kk0[i] = o0; kk1[i] = o1;
  }

  float lgc[1], lgs[1];
  lgc[0] = (g < 3) ? (bc[g] + dot64(Wc + g * 64, h)) : NEG;
  lgs[0] = (g < 3) ? (bs[g] + dot64(Ws + g * 64, h)) : NEG;

  if (blk < 512) {   // s = 0
    int cs0, ss0, loc0; float clp0, slp0, llp0;
    samp_team<1>(lgc, g, 3, kk0[0], kk1[0], b, cs0, clp0);
    samp_team<1>(lgs, g, 3, kk0[1], kk1[1], b, ss0, slp0);
    float lgl[7];
#pragma unroll
    for (int i = 0; i < 7; ++i) {
      const int cc = g + 4 * i;
      lgl[i] = (cc < 25) ? (bl[cc] + dot64(Wl + cc * 64, h)) : NEG;
    }
    samp_team<7>(lgl, g, 25, kk0[2], kk1[2], b, loc0, llp0);

    if (g == 0) {
      const int p0 = min(max(loc0, 0), 24);
      const int4 pt = ((const int4*)(canvas1 + b * 100))[p0];
      const bool ok0 = (loc0 >= 0) && (loc0 < 25) && (pt.x + pt.y + pt.z + pt.w >= 0);
      const float loc_r0 = ok0 ? 1.f : -1.f;
      const float col_r0 = ok0 ? ((cs0 == pt.x) ? 1.f : -1.f) : 0.f;
      out[0 * NB + b] = clp0;
      out[1 * NB + b] = slp0;
      out[2 * NB + b] = llp0;
      out[7 * NB + b] = loc_r0;
      out[8 * NB + b] = col_r0;
      out[9 * NB + b] = loc_r0;
    }
  } else {           // s = 1
    int cs1, ss1, ls1; float clp1, slp1, llp1;
    samp_team<1>(lgc, g, 3, kk0[3], kk1[3], b, cs1, clp1);
    samp_team<1>(lgs, g, 3, kk0[4], kk1[4], b, ss1, slp1);
    float lgp[2];
#pragma unroll
    for (int i = 0; i < 2; ++i) {
      const int cc = g + 4 * i;
      lgp[i] = bp[cc] + dot64(Wp + cc * 64, h);
    }
    samp_team<2>(lgp, g, 8, kk0[5], kk1[5], b, ls1, llp1);

    float uv8[8], w64[8], w65[8], w66[8], w67[8], wr2[8];
#pragma unroll
    for (int i = 0; i < 8; ++i) {
      const int j = g + 4 * i;
      uv8[i] = br1[j] + dot64(Wr1 + j * 68, h);
      const float* wr = Wr1 + j * 68 + 64;
      w64[i] = wr[0]; w65[i] = wr[1]; w66[i] = wr[2]; w67[i] = wr[3];
      wr2[i] = Wr2[j];
    }
    float lgA[7];
#pragma unroll
    for (int i = 0; i < 7; ++i) lgA[i] = NEG;
    const float b2 = br2[0];
#pragma unroll
    for (int p = 0; p < 25; ++p) {
      const int4 c4 = ((const int4*)(canvas0 + b * 100))[p];
      const float f0 = (float)c4.x, f1 = (float)c4.y;
      const float f2 = (float)c4.z, f3 = (float)c4.w;
      float part = 0.f;
#pragma unroll
      for (int i = 0; i < 8; ++i) {
        float hj = uv8[i];
        hj = fmaf(w64[i], f0, hj);
        hj = fmaf(w65[i], f1, hj);
        hj = fmaf(w66[i], f2, hj);
        hj = fmaf(w67[i], f3, hj);
        part = fmaf(wr2[i], fmaxf(hj, 0.f), part);
      }
      part += __shfl_xor(part, 1);
      part += __shfl_xor(part, 2);
      const float ap = b2 + part;
      if ((p & 3) == g) lgA[p >> 2] = ap;
    }
    int att_s; float alp1;
    samp_team<7>(lgA, g, 25, kk0[6], kk1[6], b, att_s, alp1);

    if (g == 0) {
      const int4 r4 = ((const int4*)(canvas0 + b * 100))[att_s];
      const int4 rr = *(const int4*)(ref + b * 4);
      const bool match = (r4.x == rr.x) && (r4.y == rr.y) &&
                         (r4.z == rr.z) && (r4.w == rr.w);
      const float att_reward = match ? 1.f : -1.f;
      const int ox = (int)((0x22001120u >> (ls1 * 4)) & 0xFu) - 1;
      const int oy = (int)((0x20200211u >> (ls1 * 4)) & 0xFu) - 1;
      const int loc1 = (r4.z + ox) * 5 + (r4.w + oy);
      const int p1 = min(max(loc1, 0), 24);
      const int4 q4 = ((const int4*)(canvas1 + b * 100))[p1];
      const bool ok1 = (loc1 >= 0) && (loc1 < 25) && (q4.x + q4.y + q4.z + q4.w >= 0);
      const float loc_r1 = ok1 ? 1.f : -1.f;
      const float col_r1 = ok1 ? ((cs1 == q4.x) ? 1.f : -1.f) : 0.f;
      out[3 * NB + b]  = clp1;
      out[4 * NB + b]  = slp1;
      out[5 * NB + b]  = llp1;
      out[6 * NB + b]  = alp1;
      out[10 * NB + b] = loc_r1;
      out[11 * NB + b] = col_r1;
      out[12 * NB + b] = loc_r1;
      out[13 * NB + b] = att_reward;
    }
  }
}

extern "C" void kernel_launch(void* const* d_in, const int* in_sizes, int n_in,
                              void* d_out, int out_size, void* d_ws, size_t ws_size,
                              hipStream_t stream) {
  const int* inst0 = (const int*)d_in[0];
  const int* inst1 = (const int*)d_in[1];
  const int* canvas0 = (const int*)d_in[2];
  const int* canvas1 = (const int*)d_in[3];
  const int* ref = (const int*)d_in[4];
  const float* embed = (const float*)d_in[5];
  const float* W_ih = (const float*)d_in[6];
  const float* W_hh = (const float*)d_in[7];
  const float* b_ih = (const float*)d_in[8];
  const float* b_hh = (const float*)d_in[9];
  const float* Wc = (const float*)d_in[10];
  const float* bc = (const float*)d_in[11];
  const float* Ws = (const float*)d_in[12];
  const float* bs = (const float*)d_in[13];
  const float* Wl = (const float*)d_in[14];
  const float* bl = (const float*)d_in[15];
  const float* Wr1 = (const float*)d_in[16];
  const float* br1 = (const float*)d_in[17];
  const float* Wr2 = (const float*)d_in[18];
  const float* br2 = (const float*)d_in[19];
  const float* Wp = (const float*)d_in[20];
  const float* bp = (const float*)d_in[21];

  float* ws = (float*)d_ws;
  float* embedWi = ws;                               // 1001*256 fp32
  unsigned short* Wsp = (unsigned short*)(ws + NV * 256);  // 3*256*64 bf16
  float* out = (float*)d_out;

  const size_t ldsBytes = HLOFF + 32 * 68 * 4;  // h dbuf + idst + hL = 38912
  k_prep<<<NV + 192, 256, 0, stream>>>(embed, W_ih, W_hh, b_ih, b_hh, embedWi, Wsp);
  k_lstm<<<1024, 512, ldsBytes, stream>>>(inst0, inst1, embedWi, Wsp,
                                          canvas0, canvas1, ref,
                                          Wc, bc, Ws, bs, Wl, bl,
                                          Wr1, br1, Wr2, br2, Wp, bp, out);
}